// Round 7
// baseline (141.483 us; speedup 1.0000x reference)
//
#include <hip/hip_runtime.h>

#define N_ 64
#define C_ 4
#define D_ 2048
#define K_ 64
#define O_ 256
#define L_ 1985
#define LB0 1024           // half-0 l-length
#define LB1 (L_ - LB0)     // 961
#define NT0 64             // tiles in half 0
#define NT1 61             // ceil(961/16)
#define XPAD2 1092         // LB0 + 64 + 4 (fp32 slice, zero-padded)
#define XCOPY2 1096        // bf16 copy stride (shorts), 8B-aligned rows
#define OPITCH2 1028       // staging pitch (floats), mod 32 == 4

typedef __attribute__((ext_vector_type(8))) short s16x8;
typedef __attribute__((ext_vector_type(4))) float f32x4;

// lgkmcnt-only barrier: global stores stay in flight across it
#define BAR_LGKM() do { \
    asm volatile("s_waitcnt lgkmcnt(0)\n\ts_barrier" ::: "memory"); \
    __builtin_amdgcn_sched_barrier(0); \
} while (0)

__device__ __forceinline__ unsigned short f2bf(float f) {
    union { float f; unsigned u; } v; v.f = f;
    unsigned u = v.u;
    u += 0x7fffu + ((u >> 16) & 1u);   // RNE
    return (unsigned short)(u >> 16);
}

__global__ __launch_bounds__(256) void prep_w(const float* __restrict__ w,
                                              unsigned short* __restrict__ wb,
                                              float* __restrict__ yn) {
    int o = blockIdx.x;
    int tid = threadIdx.x;
    int c = tid >> 6, k = tid & 63;
    size_t idx = (size_t)(o * C_ + c) * K_ + k;
    float v = w[idx];
    wb[idx] = f2bf(v);
    float s = v * v;
    for (int off = 32; off > 0; off >>= 1) s += __shfl_down(s, off, 64);
    if (k == 0) yn[o * C_ + c] = s;
}

// Block = (n,c,half-l). 512 threads / 8 waves, 78.7 KB LDS -> 2 blocks/CU.
// Co-resident independent blocks overlap: one drains to HBM while the
// other computes (the single-block barrier lockstep was the serializer).
__global__ __launch_bounds__(512) void shapelet_main(const float* __restrict__ x,
                                                     const unsigned short* __restrict__ wb,
                                                     const float* __restrict__ yn,
                                                     float* __restrict__ out) {
    __shared__ __align__(16) unsigned short xs[4][XCOPY2];
    __shared__ float xn[LB0];
    __shared__ __align__(16) float ost[16 * OPITCH2];

    int bid = blockIdx.x;
    int half = bid & 1;
    int nc = bid >> 1;
    int c = nc & (C_ - 1);
    int l0b = half * LB0;
    int LB = half ? LB1 : LB0;
    int NT = half ? NT1 : NT0;
    const float* xrow = x + (size_t)nc * D_;
    int tid = threadIdx.x;

    // 0a: fp32 x slice -> ost scratch (zero-padded)
    for (int i = tid; i < XPAD2; i += 512) {
        int g = l0b + i;
        ost[i] = (g < D_) ? xrow[g] : 0.f;
    }
    __syncthreads();
    // 0b: four 1-shifted bf16 copies + exact fp32 window norms
    for (int i = tid; i < XCOPY2; i += 512) {
        #pragma unroll
        for (int s = 0; s < 4; ++s) {
            int idx = i + s;
            xs[s][i] = (idx < XPAD2) ? f2bf(ost[idx]) : (unsigned short)0;
        }
    }
    for (int l = tid; l < LB0; l += 512) {
        float ssum = 0.f;
        #pragma unroll 16
        for (int k = 0; k < K_; ++k) { float v = ost[l + k]; ssum = fmaf(v, v, ssum); }
        xn[l] = ssum;
    }
    __syncthreads();

    int wave = tid >> 6, lane = tid & 63, lr = lane & 15, hi = lane >> 4;
    const unsigned short* xbase = &xs[lr & 3][(lr & ~3) + hi * 8];
    int dj = lane;

    for (int st = 0; st < 16; ++st) {
        // ---- compute: 16 o-rows x LB into ost (row lr pre-shifted by lr&3) ----
        int o = st * 16 + lr;
        s16x8 wfr[2];
        #pragma unroll
        for (int kk = 0; kk < 2; ++kk)
            wfr[kk] = *reinterpret_cast<const s16x8*>(
                wb + ((size_t)o * C_ + c) * K_ + kk * 32 + hi * 8);
        float ynv = yn[o * C_ + c];

        for (int t = wave; t < NT; t += 8) {
            int l0t = t * 16;
            f32x4 acc = {0.f, 0.f, 0.f, 0.f};
            #pragma unroll
            for (int kk = 0; kk < 2; ++kk) {
                const unsigned long long* p =
                    (const unsigned long long*)(xbase + l0t + kk * 32);
                union { unsigned long long u[2]; s16x8 v; } a;
                a.u[0] = p[0]; a.u[1] = p[1];
                acc = __builtin_amdgcn_mfma_f32_16x16x32_bf16(a.v, wfr[kk], acc, 0, 0, 0);
            }
            f32x4 xv = *reinterpret_cast<const f32x4*>(&xn[l0t + hi * 4]);
            f32x4 r;
            #pragma unroll
            for (int j = 0; j < 4; ++j)
                r[j] = fmaxf(xv[j] + ynv - 2.f * acc[j], 0.f) * (1.f / (float)K_);
            __builtin_memcpy(&ost[lr * OPITCH2 + (lr & 3) + l0t + hi * 4], &r, 16);
        }
        BAR_LGKM();   // stage staged; prior stores still in flight

        // ---- drain: each wave streams rows (wave, wave+8), line-aligned ----
        #pragma unroll
        for (int rr2 = 0; rr2 < 2; ++rr2) {
            int row16 = wave + rr2 * 8;
            int r_row = st * 16 + row16;
            float* gb = out + ((size_t)nc * O_ + r_row) * (size_t)L_ + l0b;
            const float* src = &ost[row16 * OPITCH2 + (row16 & 3)];
            int start = (int)(((unsigned)r_row * (unsigned)L_ + (unsigned)l0b) & 31u);
            int h = (32 - start) & 31;

            if (dj < h) gb[dj] = src[dj];                       // scalar head
            for (int pos = h + dj * 4; pos + 4 <= LB; pos += 256) {
                f32x4 v = *reinterpret_cast<const f32x4*>(src + pos); // ds_read_b128
                *reinterpret_cast<f32x4*>(gb + pos) = v;              // aligned dwordx4
            }
            int rem = (LB - h) & 3;                             // 0..3 tail dwords
            int base = LB - rem;
            if (dj < rem) gb[base + dj] = src[base + dj];
        }
        BAR_LGKM();   // drain reads done -> ost reusable; stores in flight
    }
}

extern "C" void kernel_launch(void* const* d_in, const int* in_sizes, int n_in,
                              void* d_out, int out_size, void* d_ws, size_t ws_size,
                              hipStream_t stream) {
    const float* x = (const float*)d_in[0];
    const float* w = (const float*)d_in[1];
    float* out = (float*)d_out;

    unsigned short* wb = (unsigned short*)d_ws;                    // 128 KiB
    float* yn = (float*)((char*)d_ws + (size_t)O_ * C_ * K_ * 2);  // 4 KiB

    prep_w<<<O_, 256, 0, stream>>>(w, wb, yn);
    shapelet_main<<<N_ * C_ * 2, 512, 0, stream>>>(x, wb, yn, out);
}

// Round 8
// 131.803 us; speedup vs baseline: 1.0734x; 1.0734x over previous
//
#include <hip/hip_runtime.h>

#define N_ 64
#define C_ 4
#define D_ 2048
#define K_ 64
#define O_ 256
#define L_ 1985
#define XPAD 2112          // padded x row (D_ + 64)
#define XCOPY 2116         // stride of shifted bf16 copies (shorts)
#define OPITCH 2020        // staging pitch (floats): mod 32 == 4 (bank spread)
#define NTILE 125          // ceil(L_/16)

typedef __attribute__((ext_vector_type(8))) short s16x8;
typedef __attribute__((ext_vector_type(4))) float f32x4;
typedef __attribute__((ext_vector_type(4), aligned(4))) float f32x4u;  // 4B-aligned vec store

// lgkmcnt-only barrier: global stores stay in flight across it
#define BAR_LGKM() do { \
    asm volatile("s_waitcnt lgkmcnt(0)\n\ts_barrier" ::: "memory"); \
    __builtin_amdgcn_sched_barrier(0); \
} while (0)

__device__ __forceinline__ unsigned short f2bf(float f) {
    union { float f; unsigned u; } v; v.f = f;
    unsigned u = v.u;
    u += 0x7fffu + ((u >> 16) & 1u);   // RNE
    return (unsigned short)(u >> 16);
}

__global__ __launch_bounds__(256) void prep_w(const float* __restrict__ w,
                                              unsigned short* __restrict__ wb,
                                              float* __restrict__ yn) {
    int o = blockIdx.x;
    int tid = threadIdx.x;
    int c = tid >> 6, k = tid & 63;
    size_t idx = (size_t)(o * C_ + c) * K_ + k;
    float v = w[idx];
    wb[idx] = f2bf(v);
    float s = v * v;
    for (int off = 32; off > 0; off >>= 1) s += __shfl_down(s, off, 64);
    if (k == 0) yn[o * C_ + c] = s;
}

// One block per (n,c). 16 waves. Stage: compute 16 o-rows x full L into LDS,
// then each wave drains one row as a contiguous stream of NONTEMPORAL
// dwordx4 stores (L2 no-allocate -> no dirty-eviction backpressure).
__global__ __launch_bounds__(1024) void shapelet_main(const float* __restrict__ x,
                                                      const unsigned short* __restrict__ wb,
                                                      const float* __restrict__ yn,
                                                      float* __restrict__ out) {
    __shared__ __align__(16) unsigned short xs[4][XCOPY];
    __shared__ float xn[D_];
    __shared__ __align__(16) float ost[16 * OPITCH];

    int nc = blockIdx.x;
    int c = nc & (C_ - 1);
    const float* xrow = x + (size_t)nc * D_;
    int tid = threadIdx.x;

    // phase 0a: x row -> ost (fp32 scratch)
    for (int i = tid; i < XPAD; i += 1024) ost[i] = (i < D_) ? xrow[i] : 0.f;
    __syncthreads();
    // phase 0b: four 1-shifted bf16 copies + exact fp32 window norms
    for (int i = tid; i < XCOPY; i += 1024) {
        #pragma unroll
        for (int s = 0; s < 4; ++s) {
            int idx = i + s;
            xs[s][i] = (idx < XPAD) ? f2bf(ost[idx]) : (unsigned short)0;
        }
    }
    for (int l = tid; l < D_; l += 1024) {
        float ssum = 0.f;
        #pragma unroll 16
        for (int k = 0; k < K_; ++k) { float v = ost[l + k]; ssum = fmaf(v, v, ssum); }
        xn[l] = ssum;
    }
    __syncthreads();

    int wave = tid >> 6, lane = tid & 63, lr = lane & 15, hi = lane >> 4;
    const unsigned short* xbase = &xs[lr & 3][(lr & ~3) + hi * 8];
    int dj = lane;

    for (int st = 0; st < 16; ++st) {
        // ---- compute stage st: 16 o-rows x full L into ost ----
        int o = st * 16 + lr;
        s16x8 wfr[2];
        #pragma unroll
        for (int kk = 0; kk < 2; ++kk)
            wfr[kk] = *reinterpret_cast<const s16x8*>(
                wb + ((size_t)o * C_ + c) * K_ + kk * 32 + hi * 8);
        float ynv = yn[o * C_ + c];

        for (int t = wave; t < NTILE; t += 16) {
            int l0t = t * 16;
            f32x4 acc = {0.f, 0.f, 0.f, 0.f};
            #pragma unroll
            for (int kk = 0; kk < 2; ++kk) {
                const unsigned long long* p =
                    (const unsigned long long*)(xbase + l0t + kk * 32);
                union { unsigned long long u[2]; s16x8 v; } a;
                a.u[0] = p[0]; a.u[1] = p[1];
                acc = __builtin_amdgcn_mfma_f32_16x16x32_bf16(a.v, wfr[kk], acc, 0, 0, 0);
            }
            f32x4 xv = *reinterpret_cast<const f32x4*>(&xn[l0t + hi * 4]);
            f32x4 r;
            #pragma unroll
            for (int j = 0; j < 4; ++j)
                r[j] = fmaxf(xv[j] + ynv - 2.f * acc[j], 0.f) * (1.f / (float)K_);
            *reinterpret_cast<f32x4*>(&ost[lr * OPITCH + l0t + hi * 4]) = r;
        }
        BAR_LGKM();   // staging complete

        // ---- drain: wave w streams row w with nontemporal dwordx4 ----
        float* gb = out + ((size_t)nc * O_ + st * 16 + wave) * L_;
        const float* src = &ost[wave * OPITCH];
        for (int pos = dj * 4; pos + 4 <= L_; pos += 256) {
            f32x4 v = *reinterpret_cast<const f32x4*>(src + pos);  // aligned b128
            __builtin_nontemporal_store(v, (f32x4u*)(gb + pos));   // nt dwordx4
        }
        if (dj == 0) __builtin_nontemporal_store(src[L_ - 1], gb + (L_ - 1));
        BAR_LGKM();   // drain reads done -> ost reusable; stores in flight
    }
}

extern "C" void kernel_launch(void* const* d_in, const int* in_sizes, int n_in,
                              void* d_out, int out_size, void* d_ws, size_t ws_size,
                              hipStream_t stream) {
    const float* x = (const float*)d_in[0];
    const float* w = (const float*)d_in[1];
    float* out = (float*)d_out;

    unsigned short* wb = (unsigned short*)d_ws;                    // 128 KiB
    float* yn = (float*)((char*)d_ws + (size_t)O_ * C_ * K_ * 2);  // 4 KiB

    prep_w<<<O_, 256, 0, stream>>>(w, wb, yn);
    shapelet_main<<<N_ * C_, 1024, 0, stream>>>(x, wb, yn, out);
}

// Round 9
// 121.342 us; speedup vs baseline: 1.1660x; 1.0862x over previous
//
#include <hip/hip_runtime.h>

#define N_ 64
#define C_ 4
#define D_ 2048
#define K_ 64
#define O_ 256
#define L_ 1985
#define XCOPY 2116         // stride of shifted bf16 copies (shorts)
#define OPITCH 2020        // staging pitch (floats): mod 32 == 4 (bank spread)
#define NTILE 125          // ceil(L_/16)

typedef __attribute__((ext_vector_type(8))) short s16x8;
typedef __attribute__((ext_vector_type(4))) float f32x4;

// lgkmcnt-only barrier: global stores stay in flight across it
#define BAR_LGKM() do { \
    asm volatile("s_waitcnt lgkmcnt(0)\n\ts_barrier" ::: "memory"); \
    __builtin_amdgcn_sched_barrier(0); \
} while (0)

__device__ __forceinline__ unsigned short f2bf(float f) {
    union { float f; unsigned u; } v; v.f = f;
    unsigned u = v.u;
    u += 0x7fffu + ((u >> 16) & 1u);   // RNE
    return (unsigned short)(u >> 16);
}

// weight (O,C,K) fp32 -> bf16, plus yn/64 (pre-scaled norm)
__global__ __launch_bounds__(256) void prep_w(const float* __restrict__ w,
                                              unsigned short* __restrict__ wb,
                                              float* __restrict__ ynK) {
    int o = blockIdx.x;
    int tid = threadIdx.x;
    int c = tid >> 6, k = tid & 63;
    size_t idx = (size_t)(o * C_ + c) * K_ + k;
    float v = w[idx];
    wb[idx] = f2bf(v);
    float s = v * v;
    for (int off = 32; off > 0; off >>= 1) s += __shfl_down(s, off, 64);
    if (k == 0) ynK[o * C_ + c] = s * 0.015625f;
}

// One block per (n,c), 16 waves, 16 stages. R3 burst-drain structure with the
// non-drain time minimized: cheap xn (block partial sums), no fp32 staging
// pass, static-unrolled tile loop, 3-VALU epilogue.
__global__ __launch_bounds__(1024) void shapelet_main(const float* __restrict__ x,
                                                      const unsigned short* __restrict__ wb,
                                                      const float* __restrict__ ynK,
                                                      float* __restrict__ out) {
    __shared__ __align__(16) unsigned short xs[4][XCOPY]; // xs[s][i] = bf16(x[i+s])
    __shared__ float xn[D_];                              // window sumsq / 64
    __shared__ __align__(16) float ost[16 * OPITCH];      // staging (scratch in prologue)

    int nc = blockIdx.x;
    int c = nc & (C_ - 1);
    const float* xrow = x + (size_t)nc * D_;
    int tid = threadIdx.x;

    float* z    = ost;                 // [0..2111]  x^2, zero-padded
    float* pre  = ost + 2176;          // [m*16+b]   in-block prefix sums (m<132)
    float* S16v = ost + 2176 + 2112;   // [m]        16-elem block sums

    // phase 1: bf16 copies + squares straight from global (row is L2-hot)
    for (int i = tid; i < 2112; i += 1024) {
        float v = (i < D_) ? xrow[i] : 0.f;
        z[i] = v * v;
        unsigned short b = f2bf(v);
        #pragma unroll
        for (int s = 0; s < 4; ++s) { int j = i - s; if (j >= 0) xs[s][j] = b; }
    }
    __syncthreads();
    // phase 2: 16-elem block sums + in-block prefixes (132 blocks)
    if (tid < 132) {
        float run = 0.f;
        int base = tid * 16;
        #pragma unroll
        for (int j = 0; j < 16; ++j) { pre[base + j] = run; run += z[base + j]; }
        S16v[tid] = run;
    }
    __syncthreads();
    // phase 3: xn[l] = (suffix(a,b) + S16[a+1..a+3] + prefix(a+4,b)) / 64
    for (int l = tid; l < D_; l += 1024) {
        int a = l >> 4, b = l & 15;
        float s = S16v[a] - pre[a * 16 + b] + S16v[a + 1] + S16v[a + 2]
                + S16v[a + 3] + pre[(a + 4) * 16 + b];
        xn[l] = s * 0.015625f;
    }
    __syncthreads();

    int wave = tid >> 6, lane = tid & 63, lr = lane & 15, hi = lane >> 4;
    const unsigned short* xbase = &xs[lr & 3][(lr & ~3) + hi * 8];
    int dj = lane;

    for (int st = 0; st < 16; ++st) {
        // ---- compute stage st: 16 o-rows x full L into ost ----
        int o = st * 16 + lr;
        const s16x8* wp = reinterpret_cast<const s16x8*>(
            wb + ((size_t)o * C_ + c) * K_ + hi * 8);
        s16x8 w0 = wp[0];          // k 0..31 slice
        s16x8 w1 = wp[4];          // k 32..63 slice (+32 shorts)
        float ynKv = ynK[o * C_ + c];

        #pragma unroll
        for (int i = 0; i < 8; ++i) {
            int t = wave + i * 16;
            int tc = t > 124 ? 124 : t;          // clamp: reads stay in-bounds
            int l0t = tc * 16;
            union { unsigned long long u[2]; s16x8 v; } a0, a1;
            const unsigned long long* p0 = (const unsigned long long*)(xbase + l0t);
            a0.u[0] = p0[0]; a0.u[1] = p0[1];
            const unsigned long long* p1 = (const unsigned long long*)(xbase + l0t + 32);
            a1.u[0] = p1[0]; a1.u[1] = p1[1];
            f32x4 acc = {0.f, 0.f, 0.f, 0.f};
            acc = __builtin_amdgcn_mfma_f32_16x16x32_bf16(a0.v, w0, acc, 0, 0, 0);
            acc = __builtin_amdgcn_mfma_f32_16x16x32_bf16(a1.v, w1, acc, 0, 0, 0);
            f32x4 xv = *reinterpret_cast<const f32x4*>(&xn[l0t + hi * 4]);
            f32x4 r;
            #pragma unroll
            for (int j = 0; j < 4; ++j)
                r[j] = fmaxf(fmaf(acc[j], -0.03125f, xv[j] + ynKv), 0.f);
            if (t < NTILE)
                *reinterpret_cast<f32x4*>(&ost[lr * OPITCH + l0t + hi * 4]) = r;
        }
        BAR_LGKM();   // staging complete; prior-stage stores still in flight

        // ---- drain: wave w bursts row w as one contiguous stream ----
        float* gb = out + ((size_t)nc * O_ + st * 16 + wave) * L_;
        const float* src = &ost[wave * OPITCH];
        #pragma unroll
        for (int q = 0; q < 8; ++q) {
            int pos = dj * 4 + q * 256;
            if (pos + 4 <= L_) {
                f32x4 v = *reinterpret_cast<const f32x4*>(src + pos);  // aligned b128
                __builtin_memcpy(gb + pos, &v, 16);                    // dwordx4
            }
        }
        if (dj == 0) gb[L_ - 1] = src[L_ - 1];
        BAR_LGKM();   // drain reads done -> ost reusable
    }
}

extern "C" void kernel_launch(void* const* d_in, const int* in_sizes, int n_in,
                              void* d_out, int out_size, void* d_ws, size_t ws_size,
                              hipStream_t stream) {
    const float* x = (const float*)d_in[0];
    const float* w = (const float*)d_in[1];
    float* out = (float*)d_out;

    unsigned short* wb = (unsigned short*)d_ws;                     // 128 KiB
    float* ynK = (float*)((char*)d_ws + (size_t)O_ * C_ * K_ * 2);  // 4 KiB

    prep_w<<<O_, 256, 0, stream>>>(w, wb, ynK);
    shapelet_main<<<N_ * C_, 1024, 0, stream>>>(x, wb, ynK, out);
}